// Round 1
// 233.851 us; speedup vs baseline: 1.0111x; 1.0111x over previous
//
#include <hip/hip_runtime.h>
#include <math.h>

#define NB 8
#define NC 512
#define NT 1024
#define BT (NB * NT)          // 8192 flattened (b,t) rows
#define SCALE 0.125f
#define NEG_BIG (-3.0e38f)

typedef __attribute__((ext_vector_type(8))) short short8v;   // 8 bf16 (A/B frag)
typedef __attribute__((ext_vector_type(8))) _Float16 half8v; // 8 fp16 (A/B frag)
typedef __attribute__((ext_vector_type(4))) float float4v;   // C/D frag
#define MFMA_BF16(A, B, C) __builtin_amdgcn_mfma_f32_16x16x32_bf16(A, B, C, 0, 0, 0)
#define MFMA_F16(A, B, C)  __builtin_amdgcn_mfma_f32_16x16x32_f16(A, B, C, 0, 0, 0)

__device__ __forceinline__ ushort f2bf(float f) {
    union { float f; unsigned int i; } v; v.f = f;
    unsigned int r = v.i + 0x7FFFu + ((v.i >> 16) & 1u);  // RNE
    return (ushort)(r >> 16);
}

__device__ __forceinline__ ushort f2h(float f) {
    return __builtin_bit_cast(unsigned short, (_Float16)f);
}

// P'(fp16, in LDS) * row-scale, producing the f16 MFMA A-frag.
__device__ __forceinline__ half8v scale8(short8v raw, float s) {
    half8v h = __builtin_bit_cast(half8v, raw);
    const _Float16 hs = (_Float16)s;
    half8v r;
    #pragma unroll
    for (int q = 0; q < 8; ++q) r[q] = h[q] * hs;   // v_pk_mul_f16 x4
    return r;
}

#if defined(__has_builtin)
#if __has_builtin(__builtin_amdgcn_global_load_lds)
#define HAS_GLDS 1
#endif
#endif

#ifdef HAS_GLDS
__device__ __forceinline__ void glds16(const ushort* g, ushort* l) {
    __builtin_amdgcn_global_load_lds(
        (const __attribute__((address_space(1))) unsigned int*)g,
        (__attribute__((address_space(3))) unsigned int*)l, 16, 0, 0);
}
#endif

// ---------------------------------------------------------------------------
// BK=64 tile: ROWS x 64 shorts (128B rows). LDS slot p of row r holds global
// 16B-chunk p ^ (r&7)  => every ds_read_b128 frag phase is 2-way (free, m136).
// One issue = 64 lanes x 16B = 8 rows. 4 waves cover ROWS/8 issues.
// ---------------------------------------------------------------------------
template<int ROWS>
__device__ __forceinline__ void stage64(const ushort* __restrict__ g, int rsShorts,
                                        ushort* tile, int w, int lane) {
    const int r8 = lane >> 3;                  // row within 8-row group
    const int ck = (lane & 7) ^ r8;            // global chunk fetched by this lane
    const ushort* gl = g + (size_t)r8 * rsShorts + (ck << 3);
    constexpr int ni = ROWS / 32;              // issues per wave
    #pragma unroll
    for (int s = 0; s < ni; ++s) {
        const int issue = w * ni + s;
#ifdef HAS_GLDS
        glds16(gl + (size_t)issue * 8 * rsShorts, tile + issue * 512);
#else
        const uint4 v = *(const uint4*)(gl + (size_t)issue * 8 * rsShorts);
        *(uint4*)(tile + issue * 512 + lane * 8) = v;
#endif
    }
}

// frag read: row rr (local), chunk q (0..7): swizzled address
__device__ __forceinline__ short8v frag(const ushort* tile, int rr, int q) {
    return *(const short8v*)(tile + rr * 64 + ((q ^ (rr & 7)) << 3));
}

// ---------------------------------------------------------------------------
// prep_z: z fp32 [b][c][t] -> Z bf16 token-major [comp][bt][c]  (in d_out)
// ---------------------------------------------------------------------------
__global__ __launch_bounds__(256) void prep_z_kernel(
    const float* __restrict__ zre, const float* __restrict__ zim,
    ushort* __restrict__ Z)
{
    const int t0 = blockIdx.x << 6, c0 = blockIdx.y << 6;
    const int bz = blockIdx.z, b = bz & 7, comp = bz >> 3;
    const float* src = (comp ? zim : zre) + (size_t)b * NC * NT;
    ushort* dst = Z + (size_t)(comp * NB + b) * NT * NC;
    const int tid = threadIdx.x;

    __shared__ ushort T[64][72];
    #pragma unroll
    for (int r = 0; r < 4; ++r) {
        const int cl = (tid >> 4) + r * 16;
        const int t4 = (tid & 15) << 2;
        const float4 v = *(const float4*)(src + (size_t)(c0 + cl) * NT + t0 + t4);
        T[t4 + 0][cl] = f2bf(v.x); T[t4 + 1][cl] = f2bf(v.y);
        T[t4 + 2][cl] = f2bf(v.z); T[t4 + 3][cl] = f2bf(v.w);
    }
    __syncthreads();
    const int tl = tid >> 2, cc = (tid & 3) << 4;
    ushort* op = dst + (size_t)(t0 + tl) * NC + c0 + cc;
    *(uint4*)op       = *(const uint4*)&T[tl][cc];
    *(uint4*)(op + 8) = *(const uint4*)&T[tl][cc + 8];
}

// ---------------------------------------------------------------------------
// prep_w: 4x W fp32 [d][c] -> bf16 [m][d][c] (ws)
// ---------------------------------------------------------------------------
__global__ __launch_bounds__(256) void prep_w_kernel(
    const float* __restrict__ Wq, const float* __restrict__ Wk,
    const float* __restrict__ Wv, const float* __restrict__ Wo,
    ushort* __restrict__ Wbf)
{
    const int idx = blockIdx.x * 256 + threadIdx.x;
    const int e4 = idx << 2;
    const int m = e4 >> 18;
    const int off = e4 & ((1 << 18) - 1);
    const float* Ws[4] = {Wq, Wk, Wv, Wo};
    const float4 v = *(const float4*)(Ws[m] + off);
    ushort4 o;
    o.x = f2bf(v.x); o.y = f2bf(v.y); o.z = f2bf(v.z); o.w = f2bf(v.w);
    *(ushort4*)(Wbf + ((size_t)m << 18) + off) = o;
}

// ---------------------------------------------------------------------------
// proj_qk: tile 128(bt) x 64(d); wave 64x32 computes q AND k, re+im.
// ---------------------------------------------------------------------------
__global__ __launch_bounds__(256, 2) void proj_qk_kernel(
    const ushort* __restrict__ Z, const ushort* __restrict__ Wbf,
    const float* __restrict__ phiq, const float* __restrict__ phik,
    ushort* __restrict__ qre, ushort* __restrict__ qim,
    ushort* __restrict__ kre, ushort* __restrict__ kim)
{
    const int tid = threadIdx.x;
    const int m0 = blockIdx.x << 7;
    const int d0 = blockIdx.y << 6;
    const size_t NE = (size_t)BT * NC;

    __shared__ alignas(16) ushort Zr[128 * 64], Zi[128 * 64];
    __shared__ alignas(16) ushort Wq_s[64 * 64], Wk_s[64 * 64];

    float4v accq[2][4][2] = {};
    float4v acck[2][4][2] = {};

    const int w = tid >> 6, lane = tid & 63;
    const int l15 = lane & 15, quad = lane >> 4;
    const int wm = (w & 1) << 6;
    const int wn = (w >> 1) << 5;

    for (int c0 = 0; c0 < NC; c0 += 64) {
        stage64<128>(Z + (size_t)m0 * NC + c0, NC, Zr, w, lane);
        stage64<128>(Z + NE + (size_t)m0 * NC + c0, NC, Zi, w, lane);
        stage64<64>(Wbf + (size_t)d0 * NC + c0, NC, Wq_s, w, lane);
        stage64<64>(Wbf + ((size_t)1 << 18) + (size_t)d0 * NC + c0, NC, Wk_s, w, lane);
        __syncthreads();
        #pragma unroll
        for (int kk = 0; kk < 2; ++kk) {
            const int q0 = kk * 4 + quad;
            short8v zf[2][4], wqf[2], wkf[2];
            #pragma unroll
            for (int i = 0; i < 4; ++i) {
                zf[0][i] = frag(Zr, wm + i * 16 + l15, q0);
                zf[1][i] = frag(Zi, wm + i * 16 + l15, q0);
            }
            #pragma unroll
            for (int j = 0; j < 2; ++j) {
                wqf[j] = frag(Wq_s, wn + j * 16 + l15, q0);
                wkf[j] = frag(Wk_s, wn + j * 16 + l15, q0);
            }
            #pragma unroll
            for (int c = 0; c < 2; ++c)
                #pragma unroll
                for (int i = 0; i < 4; ++i)
                    #pragma unroll
                    for (int j = 0; j < 2; ++j) {
                        accq[c][i][j] = MFMA_BF16(zf[c][i], wqf[j], accq[c][i][j]);
                        acck[c][i][j] = MFMA_BF16(zf[c][i], wkf[j], acck[c][i][j]);
                    }
        }
        __syncthreads();
    }

    #pragma unroll
    for (int j = 0; j < 2; ++j) {
        const int d = d0 + wn + j * 16 + l15;
        const float pq = phiq[d], pk = phik[d];
        const float cq = cosf(pq), sq = sinf(pq);
        const float ck = cosf(pk), sk = sinf(pk);
        #pragma unroll
        for (int i = 0; i < 4; ++i)
            #pragma unroll
            for (int r = 0; r < 4; ++r) {
                const size_t m = m0 + wm + i * 16 + quad * 4 + r;
                const size_t off = m * NC + d;
                const float ar = accq[0][i][j][r], ai = accq[1][i][j][r];
                qre[off] = f2bf(ar * cq - ai * sq);
                qim[off] = f2bf(ar * sq + ai * cq);
                const float br = acck[0][i][j][r], bi = acck[1][i][j][r];
                kre[off] = f2bf(br * ck - bi * sk);
                kim[off] = f2bf(br * sk + bi * ck);
            }
    }
}

// ---------------------------------------------------------------------------
// proj_v: tile 128(d) x 64(bt); A=Wv, B=Z -> channel-major v, re+im (FP16).
// ---------------------------------------------------------------------------
__global__ __launch_bounds__(256, 3) void proj_v_kernel(
    const ushort* __restrict__ Z, const ushort* __restrict__ Wbf,
    const float* __restrict__ phiv,
    ushort* __restrict__ vre, ushort* __restrict__ vim)
{
    const int tid = threadIdx.x;
    const int d0 = blockIdx.x << 7;
    const int bt0 = blockIdx.y << 6;
    const size_t NE = (size_t)BT * NC;

    __shared__ alignas(16) ushort Wv_s[128 * 64], Zr[64 * 64], Zi[64 * 64];
    float4v acc[2][4][2] = {};

    const int w = tid >> 6, lane = tid & 63;
    const int l15 = lane & 15, quad = lane >> 4;
    const int wm = (w & 1) << 6;
    const int wn = (w >> 1) << 5;

    for (int c0 = 0; c0 < NC; c0 += 64) {
        stage64<128>(Wbf + ((size_t)2 << 18) + (size_t)d0 * NC + c0, NC, Wv_s, w, lane);
        stage64<64>(Z + (size_t)bt0 * NC + c0, NC, Zr, w, lane);
        stage64<64>(Z + NE + (size_t)bt0 * NC + c0, NC, Zi, w, lane);
        __syncthreads();
        #pragma unroll
        for (int kk = 0; kk < 2; ++kk) {
            const int q0 = kk * 4 + quad;
            short8v wvf[4], zf[2][2];
            #pragma unroll
            for (int i = 0; i < 4; ++i)
                wvf[i] = frag(Wv_s, wm + i * 16 + l15, q0);
            #pragma unroll
            for (int j = 0; j < 2; ++j) {
                zf[0][j] = frag(Zr, wn + j * 16 + l15, q0);
                zf[1][j] = frag(Zi, wn + j * 16 + l15, q0);
            }
            #pragma unroll
            for (int c = 0; c < 2; ++c)
                #pragma unroll
                for (int i = 0; i < 4; ++i)
                    #pragma unroll
                    for (int j = 0; j < 2; ++j)
                        acc[c][i][j] = MFMA_BF16(wvf[i], zf[c][j], acc[c][i][j]);
        }
        __syncthreads();
    }

    #pragma unroll
    for (int i = 0; i < 4; ++i)
        #pragma unroll
        for (int r = 0; r < 4; ++r) {
            const int d = d0 + wm + i * 16 + quad * 4 + r;
            const float ph = phiv[d];
            const float cs = cosf(ph), sn = sinf(ph);
            #pragma unroll
            for (int j = 0; j < 2; ++j) {
                const int bt = bt0 + wn + j * 16 + l15;
                const int b = bt >> 10, t = bt & 1023;
                const size_t off = (size_t)b * NC * NT + (size_t)d * NT + t;
                const float vr = acc[0][i][j][r], vi = acc[1][i][j][r];
                vre[off] = f2h(vr * cs - vi * sn);
                vim[off] = f2h(vr * sn + vi * cs);
            }
        }
}

// ---------------------------------------------------------------------------
// scores: tile 128(t) x 128(u); heavy t-tiles first; fused re+im acc.
// Fused per-subtile softmax: writes P' = exp(S - m_sub) fp16 (row stride NT)
// and per-(row, 64u-subtile) stats (m, l).  No fp32 S materialization.
// ---------------------------------------------------------------------------
__global__ __launch_bounds__(256, 3) void scores_kernel(
    const ushort* __restrict__ qre, const ushort* __restrict__ qim,
    const ushort* __restrict__ kre, const ushort* __restrict__ kim,
    ushort* __restrict__ Pp, float2* __restrict__ stats)
{
    const int u0b = blockIdx.x << 7;
    const int t0b = (gridDim.y - 1 - blockIdx.y) << 7;   // heavy first
    if (u0b > t0b) return;
    const int b = blockIdx.z;
    const int tid = threadIdx.x;
    const size_t qb = (size_t)b * NT * NC;

    __shared__ alignas(16) ushort Qr[128 * 64], Qi[128 * 64], Kr[128 * 64], Ki[128 * 64];
    float4v acc[4][4] = {};

    const int w = tid >> 6, lane = tid & 63;
    const int l15 = lane & 15, quad = lane >> 4;
    const int wm = (w & 1) << 6;
    const int wn = (w >> 1) << 6;

    for (int c0 = 0; c0 < NC; c0 += 64) {
        stage64<128>(qre + qb + (size_t)t0b * NC + c0, NC, Qr, w, lane);
        stage64<128>(qim + qb + (size_t)t0b * NC + c0, NC, Qi, w, lane);
        stage64<128>(kre + qb + (size_t)u0b * NC + c0, NC, Kr, w, lane);
        stage64<128>(kim + qb + (size_t)u0b * NC + c0, NC, Ki, w, lane);
        __syncthreads();
        #pragma unroll
        for (int kk = 0; kk < 2; ++kk) {
            const int q0 = kk * 4 + quad;
            short8v qf[2][4], kf[2][4];
            #pragma unroll
            for (int i = 0; i < 4; ++i) {
                qf[0][i] = frag(Qr, wm + i * 16 + l15, q0);
                qf[1][i] = frag(Qi, wm + i * 16 + l15, q0);
                kf[0][i] = frag(Kr, wn + i * 16 + l15, q0);
                kf[1][i] = frag(Ki, wn + i * 16 + l15, q0);
            }
            #pragma unroll
            for (int i = 0; i < 4; ++i)
                #pragma unroll
                for (int j = 0; j < 4; ++j) {
                    acc[i][j] = MFMA_BF16(qf[0][i], kf[0][j], acc[i][j]);
                    acc[i][j] = MFMA_BF16(qf[1][i], kf[1][j], acc[i][j]);
                }
        }
        __syncthreads();
    }

    // ---- fused per-64u-subtile softmax stats + P' write ----
    // Each wave owns rows [wm,wm+64) x u-subtile (u0b+wn .. +64).
    // For fixed (i,r) a row's 4 j-values live across the 16 l15 lanes of a
    // quad: butterfly over lane bits 0..3 reduces the full 64-u subtile.
    const int sub = (u0b + wn) >> 6;            // global 64u-subtile index
    float2* st = stats + (size_t)(b * 16 + sub) * NT;
    ushort* Pb = Pp + (size_t)b * NT * NT;
    #pragma unroll
    for (int i = 0; i < 4; ++i)
        #pragma unroll
        for (int r = 0; r < 4; ++r) {
            const int t = t0b + wm + i * 16 + quad * 4 + r;
            float v[4]; float m = NEG_BIG;
            #pragma unroll
            for (int j = 0; j < 4; ++j) {
                const int u = u0b + wn + j * 16 + l15;
                const float x = (u > t) ? NEG_BIG : acc[i][j][r] * SCALE;
                v[j] = x; m = fmaxf(m, x);
            }
            #pragma unroll
            for (int d = 1; d < 16; d <<= 1) m = fmaxf(m, __shfl_xor(m, d, 64));
            float l = 0.f; ushort ph[4];
            #pragma unroll
            for (int j = 0; j < 4; ++j) {
                const float e = __expf(v[j] - m);   // masked: exp(-3e38-m)=0
                l += e;
                ph[j] = f2h(e);
            }
            #pragma unroll
            for (int d = 1; d < 16; d <<= 1) l += __shfl_xor(l, d, 64);
            ushort* pr = Pb + (size_t)t * NT + u0b + wn + l15;
            #pragma unroll
            for (int j = 0; j < 4; ++j) pr[j * 16] = ph[j];
            if (l15 == 0) st[t] = make_float2(m, l);
            // fully-masked subtile: m=NEG_BIG, l=64, P'=1 -- harmless, its
            // pv scale exp(m-M)/L underflows to exactly 0.
        }
}

// ---------------------------------------------------------------------------
// pv: tile 128(t) x 64(c); heavy t-tiles first; A=P' fp16 (scaled by
// per-(row,subtile) softmax scale from stats), B=V fp16 channel-major.
// ---------------------------------------------------------------------------
__global__ __launch_bounds__(256, 3) void pv_kernel(
    const ushort* __restrict__ Pp, const float2* __restrict__ stats,
    const ushort* __restrict__ vre, const ushort* __restrict__ vim,
    ushort* __restrict__ Ore, ushort* __restrict__ Oim)
{
    const int c0b = blockIdx.x << 6;
    const int t0b = (gridDim.y - 1 - blockIdx.y) << 7;   // heavy first
    const int b = blockIdx.z;
    const int tid = threadIdx.x;
    const ushort* P = Pp + ((size_t)b * NT + t0b) * NT;
    const size_t vb = (size_t)b * NC * NT;
    const int iters = (t0b + 128) >> 6;

    __shared__ alignas(16) ushort Ps[128 * 64], Vr[64 * 64], Vi[64 * 64];
    __shared__ float sLds[128][17];              // per-(row, subtile) scale
    float4v acc[2][4][2] = {};

    const int w = tid >> 6, lane = tid & 63;
    const int l15 = lane & 15, quad = lane >> 4;
    const int wm = (w & 1) << 6;
    const int wn = (w >> 1) << 5;

    // prologue: combine subtile stats -> scale_s = exp(m_s - M) / L
    if (tid < 128) {
        const int t = t0b + tid;
        float M = NEG_BIG;
        for (int s = 0; s < iters; ++s)
            M = fmaxf(M, stats[(size_t)(b * 16 + s) * NT + t].x);
        float L = 0.f;
        for (int s = 0; s < iters; ++s) {
            const float2 v = stats[(size_t)(b * 16 + s) * NT + t];
            const float e = __expf(v.x - M);
            sLds[tid][s] = e;
            L += e * v.y;
        }
        const float inv = 1.0f / L;
        for (int s = 0; s < iters; ++s) sLds[tid][s] *= inv;
    }
    // visibility of sLds is covered by the first post-stage __syncthreads

    for (int it = 0; it < iters; ++it) {
        const int u0 = it << 6;
        stage64<128>(P + u0, NT, Ps, w, lane);
        stage64<64>(vre + vb + (size_t)c0b * NT + u0, NT, Vr, w, lane);
        stage64<64>(vim + vb + (size_t)c0b * NT + u0, NT, Vi, w, lane);
        __syncthreads();
        #pragma unroll
        for (int kk = 0; kk < 2; ++kk) {
            const int q0 = kk * 4 + quad;
            half8v pf[4], vf[2][2];
            #pragma unroll
            for (int i = 0; i < 4; ++i) {
                const int row = wm + i * 16 + l15;
                pf[i] = scale8(frag(Ps, row, q0), sLds[row][it]);
            }
            #pragma unroll
            for (int j = 0; j < 2; ++j) {
                vf[0][j] = __builtin_bit_cast(half8v, frag(Vr, wn + j * 16 + l15, q0));
                vf[1][j] = __builtin_bit_cast(half8v, frag(Vi, wn + j * 16 + l15, q0));
            }
            #pragma unroll
            for (int c = 0; c < 2; ++c)
                #pragma unroll
                for (int i = 0; i < 4; ++i)
                    #pragma unroll
                    for (int j = 0; j < 2; ++j)
                        acc[c][i][j] = MFMA_F16(pf[i], vf[c][j], acc[c][i][j]);
        }
        __syncthreads();
    }
    #pragma unroll
    for (int i = 0; i < 4; ++i)
        #pragma unroll
        for (int j = 0; j < 2; ++j)
            #pragma unroll
            for (int r = 0; r < 4; ++r) {
                const int t = t0b + wm + i * 16 + quad * 4 + r;
                const int c = c0b + wn + j * 16 + l15;
                const size_t off = ((size_t)b * NT + t) * NC + c;
                Ore[off] = f2bf(acc[0][i][j][r]);
                Oim[off] = f2bf(acc[1][i][j][r]);
            }
}

// ---------------------------------------------------------------------------
// proj_out: tile 128(d) x 64(bt); A=Wo, B=O. fp32 -> d_out [b][d][t].
// ---------------------------------------------------------------------------
__global__ __launch_bounds__(256, 3) void proj_out_kernel(
    const ushort* __restrict__ Ore, const ushort* __restrict__ Oim,
    const ushort* __restrict__ Wbf, const float* __restrict__ phio,
    float* __restrict__ outRe, float* __restrict__ outIm)
{
    const int tid = threadIdx.x;
    const int d0 = blockIdx.x << 7;
    const int bt0 = blockIdx.y << 6;

    __shared__ alignas(16) ushort Wo_s[128 * 64], Or_s[64 * 64], Oi_s[64 * 64];
    float4v acc[2][4][2] = {};

    const int w = tid >> 6, lane = tid & 63;
    const int l15 = lane & 15, quad = lane >> 4;
    const int wm = (w & 1) << 6;
    const int wn = (w >> 1) << 5;

    for (int c0 = 0; c0 < NC; c0 += 64) {
        stage64<128>(Wbf + ((size_t)3 << 18) + (size_t)d0 * NC + c0, NC, Wo_s, w, lane);
        stage64<64>(Ore + (size_t)bt0 * NC + c0, NC, Or_s, w, lane);
        stage64<64>(Oim + (size_t)bt0 * NC + c0, NC, Oi_s, w, lane);
        __syncthreads();
        #pragma unroll
        for (int kk = 0; kk < 2; ++kk) {
            const int q0 = kk * 4 + quad;
            short8v wof[4], of[2][2];
            #pragma unroll
            for (int i = 0; i < 4; ++i)
                wof[i] = frag(Wo_s, wm + i * 16 + l15, q0);
            #pragma unroll
            for (int j = 0; j < 2; ++j) {
                of[0][j] = frag(Or_s, wn + j * 16 + l15, q0);
                of[1][j] = frag(Oi_s, wn + j * 16 + l15, q0);
            }
            #pragma unroll
            for (int c = 0; c < 2; ++c)
                #pragma unroll
                for (int i = 0; i < 4; ++i)
                    #pragma unroll
                    for (int j = 0; j < 2; ++j)
                        acc[c][i][j] = MFMA_BF16(wof[i], of[c][j], acc[c][i][j]);
        }
        __syncthreads();
    }

    #pragma unroll
    for (int i = 0; i < 4; ++i)
        #pragma unroll
        for (int r = 0; r < 4; ++r) {
            const int d = d0 + wm + i * 16 + quad * 4 + r;
            const float ph = phio[d];
            const float cs = cosf(ph), sn = sinf(ph);
            #pragma unroll
            for (int j = 0; j < 2; ++j) {
                const int bt = bt0 + wn + j * 16 + l15;
                const int b = bt >> 10, t = bt & 1023;
                const size_t off = (size_t)b * NC * NT + (size_t)d * NT + t;
                const float re2 = acc[0][i][j][r], im2 = acc[1][i][j][r];
                outRe[off] = re2 * cs - im2 * sn;
                outIm[off] = re2 * sn + im2 * cs;
            }
        }
}

extern "C" void kernel_launch(void* const* d_in, const int* in_sizes, int n_in,
                              void* d_out, int out_size, void* d_ws, size_t ws_size,
                              hipStream_t stream) {
    (void)in_sizes; (void)n_in; (void)out_size; (void)ws_size;
    const float* z_re  = (const float*)d_in[0];
    const float* z_im  = (const float*)d_in[1];
    const float* Wq    = (const float*)d_in[2];
    const float* phi_q = (const float*)d_in[3];
    const float* Wk    = (const float*)d_in[4];
    const float* phi_k = (const float*)d_in[5];
    const float* Wv    = (const float*)d_in[6];
    const float* phi_v = (const float*)d_in[7];
    const float* Wo    = (const float*)d_in[8];
    const float* phi_o = (const float*)d_in[9];

    const size_t NE = (size_t)BT * NC;     // 4,194,304
    ushort* ws  = (ushort*)d_ws;
    ushort* qre = ws + 0 * NE; ushort* qim = ws + 1 * NE;   // aliased as O after scores
    ushort* kre = ws + 2 * NE; ushort* kim = ws + 3 * NE;
    ushort* vre = ws + 4 * NE; ushort* vim = ws + 5 * NE;   // channel-major fp16
    ushort* Wbf = ws + 6 * NE;                              // 2 MiB
    // d_out doubles as scratch:
    //   [0      , 16.8MB) : Z bf16 (dead after proj_qk/proj_v) -> stats (1MB)
    //   [16.8MB , 33.5MB) : P' fp16 (written by scores, read by pv)
    // proj_out finally overwrites all of d_out with outRe/outIm.
    ushort* Z  = (ushort*)d_out;
    ushort* Pp = (ushort*)d_out + 2 * NE;
    float2* stats = (float2*)d_out;        // 8 x 16 x 1024 float2 = 1 MiB

    const dim3 blk(256);
    hipLaunchKernelGGL(prep_z_kernel, dim3(NT / 64, NC / 64, NB * 2), blk, 0, stream, z_re, z_im, Z);
    hipLaunchKernelGGL(prep_w_kernel, dim3(1024), blk, 0, stream, Wq, Wk, Wv, Wo, Wbf);
    hipLaunchKernelGGL(proj_qk_kernel, dim3(BT / 128, NC / 64), blk, 0, stream,
                       Z, Wbf, phi_q, phi_k, qre, qim, kre, kim);
    hipLaunchKernelGGL(proj_v_kernel, dim3(NC / 128, BT / 64), blk, 0, stream,
                       Z, Wbf, phi_v, vre, vim);
    hipLaunchKernelGGL(scores_kernel, dim3(NT / 128, NT / 128, NB), blk, 0, stream,
                       qre, qim, kre, kim, Pp, stats);
    hipLaunchKernelGGL(pv_kernel, dim3(NC / 64, NT / 128, NB), blk, 0, stream,
                       Pp, stats, vre, vim, qre, qim);
    hipLaunchKernelGGL(proj_out_kernel, dim3(NC / 128, BT / 64), blk, 0, stream,
                       qre, qim, Wbf, phi_o, (float*)d_out, (float*)d_out + NE);
}